// Round 6
// baseline (272.600 us; speedup 1.0000x reference)
//
#include <hip/hip_runtime.h>

// out[b,j,hw] = exp( sum_i log(relu(x[b,i,hw])+0.1) * E[i,j] ) + bias[j]
// x: (B=32, NC=64, H=128, W=128) fp32.
#define NCH 64
#define HWSZ 16384             // 128*128
#define NPOINTS (32 * HWSZ)    // 524288

// Pre-kernel: E (i-major) -> ET (j-major) in d_ws, so the main kernel's
// per-j row is contiguous and SMEM-loadable (s_load_dwordx16 x4 = 64 SGPRs,
// fits the ~102-SGPR budget; R4's i-major needed 4 rows at once -> thrash).
__global__ __launch_bounds__(256) void transpose_E_kernel(
    const float* __restrict__ E, float* __restrict__ ET)
{
    const int t = threadIdx.x;
    #pragma unroll
    for (int k = 0; k < 16; ++k) {
        const int o = k * 256 + t;          // output index o = j*64 + i
        const int j = o >> 6, i = o & 63;
        ET[o] = E[i * NCH + j];             // coalesced writes, 4 KB total
    }
}

// j-outer structure: (1) all 64 x loads issued up front (deep VMEM pipeline;
// R4/R5 had only 4 in flight -> latency-bound at 2x busy time), (2) per-j dot
// product with 4 partial accumulators (no acc array across a runtime loop ->
// no AGPR/scratch trap), immediate store. One pass over x = minimal HBM.
__global__ __launch_bounds__(256, 4) void fused_log_einsum_exp(
    const float* __restrict__ x,
    const float* __restrict__ ET,    // (64,64) j-major: ET[j*64+i]
    const float* __restrict__ bias,  // (64)
    float* __restrict__ out)
{
    const int p  = blockIdx.x * 256 + threadIdx.x;  // one spatial point/thread
    const int b  = p >> 14;          // p / HWSZ
    const int hw = p & (HWSZ - 1);   // p % HWSZ

    const float* xp = x   + (size_t)b * NCH * HWSZ + hw;
    float*       op = out + (size_t)b * NCH * HWSZ + hw;

    // Phase 1: issue all 64 coalesced loads, then log. lx[] fully unrolled
    // everywhere (static indices -> SROA -> VGPRs).
    float lx[NCH];
    #pragma unroll
    for (int i = 0; i < NCH; ++i) lx[i] = xp[(size_t)i * HWSZ];
    #pragma unroll
    for (int i = 0; i < NCH; ++i) lx[i] = __logf(fmaxf(lx[i], 0.0f) + 0.1f);

    // Phase 2: j-outer (runtime, uniform). Per j: one contiguous ET row via
    // SMEM, 64 fmacs into 4 ILP partials, store. Stores spread across the
    // loop and never block.
    #pragma unroll 1
    for (int j = 0; j < NCH; ++j) {
        const float* Er = ET + j * NCH;     // uniform -> s_load_dwordx16 x4
        float a0 = 0.f, a1 = 0.f, a2 = 0.f, a3 = 0.f;
        #pragma unroll
        for (int i = 0; i < NCH; i += 4) {
            a0 = fmaf(lx[i + 0], Er[i + 0], a0);
            a1 = fmaf(lx[i + 1], Er[i + 1], a1);
            a2 = fmaf(lx[i + 2], Er[i + 2], a2);
            a3 = fmaf(lx[i + 3], Er[i + 3], a3);
        }
        op[(size_t)j * HWSZ] = __expf((a0 + a1) + (a2 + a3)) + bias[j];
    }
}

extern "C" void kernel_launch(void* const* d_in, const int* in_sizes, int n_in,
                              void* d_out, int out_size, void* d_ws, size_t ws_size,
                              hipStream_t stream) {
    const float* x    = (const float*)d_in[0];
    const float* E    = (const float*)d_in[1];   // (64,64,1,1) -> [i*64+j]
    const float* bias = (const float*)d_in[2];   // (64,1,1)
    float* out = (float*)d_out;
    float* ET  = (float*)d_ws;                   // 16 KiB scratch (re-poisoned
                                                 // each call -> re-transpose)

    hipLaunchKernelGGL(transpose_E_kernel, dim3(1), dim3(256), 0, stream, E, ET);
    hipLaunchKernelGGL(fused_log_einsum_exp, dim3(NPOINTS / 256), dim3(256), 0,
                       stream, x, ET, bias, out);
}